// Round 2
// baseline (9164.615 us; speedup 1.0000x reference)
//
#include <hip/hip_runtime.h>
#include <math.h>

constexpr int NY_ = 320, NX_ = 320, NT_ = 160, SHOTS_ = 2, NSRC_ = 8, NREC_ = 96;
constexpr float DT_  = 4.0e-4f;
constexpr float C1_  = 9.0f / 8.0f;
constexpr float C2_  = -1.0f / 24.0f;
constexpr float IDH_ = 0.25f;           // 1/DH, exact
constexpr int   NP_   = NY_ * NX_;
constexpr int   NBLK_ = 200;            // 200 blocks x 512 thr = 102400 = NP_
constexpr int   REC_OFF_ = 10 * NP_;            // floats; rec = NT*SHOTS*NREC = 30720
constexpr int   BAR_OFF_ = 10 * NP_ + 32768;    // floats; barrier words live here

// out-of-range taps read 0 — exactly equivalent to jnp.roll wraparound because
// wrapped taps (reach <= 2) always land in the 2-wide edge-masked (zero) border.
__device__ __forceinline__ float gld(const float* __restrict__ p, int y, int x) {
    return ((unsigned)y < (unsigned)NY_ && (unsigned)x < (unsigned)NX_) ? p[y * NX_ + x] : 0.0f;
}

// Grid barrier: thread 0 per block. __threadfence() = agent-scope fence ->
// L2 writeback/invalidate (cross-XCD coherence) + covers this CU's L1.
// Every block runs it on its own CU/XCD, so all caches are handled.
__device__ __forceinline__ void gbar(unsigned* cnt, unsigned* gen, unsigned phase) {
    __syncthreads();   // drains vmcnt: all this block's stores are in L2
    if (threadIdx.x == 0 && threadIdx.y == 0) {
        __threadfence();   // release: flush our XCD L2
        if (__hip_atomic_fetch_add(cnt, 1u, __ATOMIC_ACQ_REL, __HIP_MEMORY_SCOPE_AGENT) == NBLK_ - 1u) {
            __hip_atomic_store(cnt, 0u, __ATOMIC_RELAXED, __HIP_MEMORY_SCOPE_AGENT);
            __hip_atomic_store(gen, phase, __ATOMIC_RELEASE, __HIP_MEMORY_SCOPE_AGENT);
        } else {
            while (__hip_atomic_load(gen, __ATOMIC_ACQUIRE, __HIP_MEMORY_SCOPE_AGENT) < phase) {
                __builtin_amdgcn_s_sleep(2);
            }
        }
        __threadfence();   // acquire: invalidate L1/L2 before reading others' data
    }
    __syncthreads();
}

__global__ void init_kernel(unsigned* __restrict__ bar) {
    if (threadIdx.x < 8) bar[threadIdx.x] = 0u;
}

__global__ __launch_bounds__(512)
void elastic_kernel(const float* __restrict__ lamb, const float* __restrict__ mu,
                    const float* __restrict__ buoy, const float* __restrict__ amps,
                    const int* __restrict__ src_loc, const int* __restrict__ rec_loc,
                    float* __restrict__ out, float* __restrict__ ws)
{
    const int x = blockIdx.x * 64 + threadIdx.x;   // grid (5,40), block (64,8)
    const int y = blockIdx.y * 8 + threadIdx.y;
    const int c = y * NX_ + x;
    unsigned* bar_cnt = (unsigned*)(ws + BAR_OFF_);
    unsigned* bar_gen = bar_cnt + 1;
    unsigned  phase = 0;

    // --- PML decay factors, computed in double to match numpy ---
    const double d0 = 3.0 * 1600.0 * log(1000.0) / (2.0 * 20.0 * 4.0);
    double py = 0.0, px = 0.0;
    if (y < 20)             { double t = (20.0 - y) / 20.0;           py = t * t; }
    else if (y >= NY_ - 20) { double t = (y - (NY_ - 1 - 20)) / 20.0; py = t * t; }
    if (x < 20)             { double t = (20.0 - x) / 20.0;           px = t * t; }
    else if (x >= NX_ - 20) { double t = (x - (NX_ - 1 - 20)) / 20.0; px = t * t; }
    const float by = (float)exp(-d0 * py * 4.0e-4);
    const float bx = (float)exp(-d0 * px * 4.0e-4);
    const float bym1 = by - 1.0f, bxm1 = bx - 1.0f;
    const float mk = (y < 2 || y >= NY_ - 2 || x < 2 || x >= NX_ - 2) ? 0.0f : 1.0f;

    const float la  = lamb[c];
    const float muv = mu[c];
    const float bu  = buoy[c];
    const float l2m = la + 2.0f * muv;

    // per-thread source-match bitmask (src_buoy == this cell's buoyancy)
    unsigned smask = 0;
    for (int s = 0; s < SHOTS_; ++s)
        for (int j = 0; j < NSRC_; ++j) {
            int sy = src_loc[(s * NSRC_ + j) * 2 + 0];
            int sx = src_loc[(s * NSRC_ + j) * 2 + 1];
            if (sy == y && sx == x) smask |= 1u << (s * NSRC_ + j);
        }

    float* pvy[SHOTS_]; float* pvx[SHOTS_]; float* psyy[SHOTS_]; float* psxy[SHOTS_]; float* psxx[SHOTS_];
    #pragma unroll
    for (int s = 0; s < SHOTS_; ++s) {
        pvy[s]  = ws + (0 * SHOTS_ + s) * NP_;
        pvx[s]  = ws + (1 * SHOTS_ + s) * NP_;
        psyy[s] = ws + (2 * SHOTS_ + s) * NP_;
        psxy[s] = ws + (3 * SHOTS_ + s) * NP_;
        psxx[s] = ws + (4 * SHOTS_ + s) * NP_;
    }
    float* rec = ws + REC_OFF_;   // [NT][SHOTS*NREC]

    // wave-field self values + all 8 CPML memory vars live in registers
    float vy[SHOTS_]  = {0, 0}, vx[SHOTS_]  = {0, 0};
    float syy[SHOTS_] = {0, 0}, sxy[SHOTS_] = {0, 0}, sxx[SHOTS_] = {0, 0};
    float msyyy[SHOTS_] = {0, 0}, msxyy[SHOTS_] = {0, 0}, msxyx[SHOTS_] = {0, 0}, msxxx[SHOTS_] = {0, 0};
    float mvyy[SHOTS_]  = {0, 0}, mvyx[SHOTS_]  = {0, 0}, mvxy[SHOTS_]  = {0, 0}, mvxx[SHOTS_]  = {0, 0};

    // zero-init global wave fields (ws is poisoned 0xAA before every launch)
    #pragma unroll
    for (int s = 0; s < SHOTS_; ++s) {
        pvy[s][c] = 0.f; pvx[s][c] = 0.f; psyy[s][c] = 0.f; psxy[s][c] = 0.f; psxx[s][c] = 0.f;
    }

    gbar(bar_cnt, bar_gen, ++phase);

    const int  tid      = threadIdx.y * 64 + threadIdx.x;
    const bool recorder = (blockIdx.x == 0 && blockIdx.y == 0);

    for (int t = 0; t < NT_; ++t) {
        // ---------- velocity phase ----------
        #pragma unroll
        for (int s = 0; s < SHOTS_; ++s) {
            const float* S_yy = psyy[s]; const float* S_xy = psxy[s]; const float* S_xx = psxx[s];
            float d, ay, ax;
            // d = D-_y(syy)
            d = (C1_ * (syy[s] - gld(S_yy, y - 1, x)) + C2_ * (gld(S_yy, y + 1, x) - gld(S_yy, y - 2, x))) * IDH_;
            msyyy[s] = by * msyyy[s] + bym1 * d;
            ay = d + msyyy[s];
            // d = D+_x(sxy)
            d = (C1_ * (gld(S_xy, y, x + 1) - sxy[s]) + C2_ * (gld(S_xy, y, x + 2) - gld(S_xy, y, x - 1))) * IDH_;
            msxyx[s] = bx * msxyx[s] + bxm1 * d;
            ay = ay + d + msxyx[s];
            vy[s] = vy[s] + DT_ * bu * ay;
            // d = D-_x(sxx)
            d = (C1_ * (sxx[s] - gld(S_xx, y, x - 1)) + C2_ * (gld(S_xx, y, x + 1) - gld(S_xx, y, x - 2))) * IDH_;
            msxxx[s] = bx * msxxx[s] + bxm1 * d;
            ax = d + msxxx[s];
            // d = D+_y(sxy)
            d = (C1_ * (gld(S_xy, y + 1, x) - sxy[s]) + C2_ * (gld(S_xy, y + 2, x) - gld(S_xy, y - 1, x))) * IDH_;
            msxyy[s] = by * msxyy[s] + bym1 * d;
            ax = ax + d + msxyy[s];
            vx[s] = vx[s] + DT_ * bu * ax;
            // source injection (before mask; sources are interior)
            unsigned m = (smask >> (s * NSRC_)) & 0xFFu;
            if (m) {
                for (int j = 0; j < NSRC_; ++j)
                    if (m & (1u << j)) vy[s] = vy[s] + DT_ * amps[(s * NSRC_ + j) * NT_ + t] * bu;
            }
            vy[s] *= mk; vx[s] *= mk;
            pvy[s][c] = vy[s]; pvx[s][c] = vx[s];
        }

        gbar(bar_cnt, bar_gen, ++phase);

        // ---------- record receivers (vy is final for this step) ----------
        if (recorder && tid < SHOTS_ * NREC_) {
            int s  = tid / NREC_, r = tid % NREC_;
            int ry = rec_loc[(s * NREC_ + r) * 2 + 0];
            int rx = rec_loc[(s * NREC_ + r) * 2 + 1];
            rec[t * (SHOTS_ * NREC_) + tid] = pvy[s][ry * NX_ + rx];
        }

        // ---------- stress phase ----------
        #pragma unroll
        for (int s = 0; s < SHOTS_; ++s) {
            const float* Vy = pvy[s]; const float* Vx = pvx[s];
            float d, e1, e2, g;
            // d = D+_y(vy)
            d = (C1_ * (gld(Vy, y + 1, x) - vy[s]) + C2_ * (gld(Vy, y + 2, x) - gld(Vy, y - 1, x))) * IDH_;
            mvyy[s] = by * mvyy[s] + bym1 * d;
            e1 = d + mvyy[s];
            // d = D-_x(vx)
            d = (C1_ * (vx[s] - gld(Vx, y, x - 1)) + C2_ * (gld(Vx, y, x + 1) - gld(Vx, y, x - 2))) * IDH_;
            mvxx[s] = bx * mvxx[s] + bxm1 * d;
            e2 = d + mvxx[s];
            syy[s] = (syy[s] + DT_ * (l2m * e1 + la * e2)) * mk;
            sxx[s] = (sxx[s] + DT_ * (l2m * e2 + la * e1)) * mk;
            // d = D+_x(vy)
            d = (C1_ * (gld(Vy, y, x + 1) - vy[s]) + C2_ * (gld(Vy, y, x + 2) - gld(Vy, y, x - 1))) * IDH_;
            mvyx[s] = bx * mvyx[s] + bxm1 * d;
            g = d + mvyx[s];
            // d = D-_y(vx)
            d = (C1_ * (vx[s] - gld(Vx, y - 1, x)) + C2_ * (gld(Vx, y + 1, x) - gld(Vx, y - 2, x))) * IDH_;
            mvxy[s] = by * mvxy[s] + bym1 * d;
            g = g + d + mvxy[s];
            sxy[s] = (sxy[s] + DT_ * muv * g) * mk;
            psyy[s][c] = syy[s]; psxy[s][c] = sxy[s]; psxx[s][c] = sxx[s];
        }

        gbar(bar_cnt, bar_gen, ++phase);
    }

    // ---------- final output: out[s][r][t] = 0.5*(rec[t] + rec[t+1]) ----------
    const int gid = (blockIdx.y * gridDim.x + blockIdx.x) * 512 + tid;
    if (gid < SHOTS_ * NREC_ * (NT_ - 1)) {
        int t  = gid % (NT_ - 1);
        int sr = gid / (NT_ - 1);
        int r  = sr % NREC_;
        int s  = sr / NREC_;
        float a = rec[t       * (SHOTS_ * NREC_) + s * NREC_ + r];
        float b = rec[(t + 1) * (SHOTS_ * NREC_) + s * NREC_ + r];
        out[gid] = 0.5f * (a + b);
    }
}

extern "C" void kernel_launch(void* const* d_in, const int* in_sizes, int n_in,
                              void* d_out, int out_size, void* d_ws, size_t ws_size,
                              hipStream_t stream)
{
    const float* lamb = (const float*)d_in[0];
    const float* mu   = (const float*)d_in[1];
    const float* buoy = (const float*)d_in[2];
    const float* amps = (const float*)d_in[3];
    const int*   src  = (const int*)d_in[4];
    const int*   recl = (const int*)d_in[5];
    float* out = (float*)d_out;
    float* ws  = (float*)d_ws;

    unsigned* bar = (unsigned*)(ws + BAR_OFF_);
    init_kernel<<<dim3(1), dim3(64), 0, stream>>>(bar);

    dim3 grid(5, 40, 1), block(64, 8, 1);
    elastic_kernel<<<grid, block, 0, stream>>>(lamb, mu, buoy, amps, src, recl, out, ws);
}

// Round 3
// 2255.056 us; speedup vs baseline: 4.0640x; 4.0640x over previous
//
#include <hip/hip_runtime.h>
#include <math.h>

constexpr int NY_ = 320, NX_ = 320, NT_ = 160, SHOTS_ = 2, NSRC_ = 8, NREC_ = 96;
constexpr float DT_  = 4.0e-4f;
constexpr float C1_  = 9.0f / 8.0f;
constexpr float C2_  = -1.0f / 24.0f;
constexpr float IDH_ = 0.25f;           // 1/DH, exact
constexpr int   NP_   = NY_ * NX_;
constexpr unsigned NBLK_ = 200;         // 200 blocks x 512 thr = 102400 = NP_
constexpr int   REC_OFF_ = 10 * NP_;            // floats; rec = NT*SHOTS*NREC = 30720
constexpr int   BAR_OFF_ = 10 * NP_ + 32768;    // floats; barrier counter lives here

// ---- coherent (Infinity-Cache-backed) field access: relaxed agent-scope
// atomics compile to global_load/store sc0 sc1 -> bypass L1+L2, served by the
// IF (the agent coherence point on multi-XCD gfx950). No wbl2/inv ever needed.
__device__ __forceinline__ float cld(const float* p) {
    return __hip_atomic_load(p, __ATOMIC_RELAXED, __HIP_MEMORY_SCOPE_AGENT);
}
__device__ __forceinline__ void cst(float* p, float v) {
    __hip_atomic_store(p, v, __ATOMIC_RELAXED, __HIP_MEMORY_SCOPE_AGENT);
}

// out-of-range taps read 0 — exactly equivalent to jnp.roll wraparound because
// wrapped taps (reach <= 2) always land in the 2-wide edge-masked (zero) border.
__device__ __forceinline__ float gld(const float* __restrict__ p, int y, int x) {
    return ((unsigned)y < (unsigned)NY_ && (unsigned)x < (unsigned)NX_) ? cld(p + y * NX_ + x) : 0.0f;
}

// Grid barrier: monotonic reset-free counter. All cross-block data moves via
// sc1 accesses (globally visible once vmcnt retires), and __syncthreads
// already drains vmcnt(0) per wave, so no cache-flush fences are required.
__device__ __forceinline__ void gbar(unsigned* cnt, unsigned phase) {
    __syncthreads();                       // drains vmcnt: block's sc1 stores visible
    if (threadIdx.x == 0 && threadIdx.y == 0) {
        asm volatile("s_waitcnt vmcnt(0)" ::: "memory");
        unsigned target = phase * NBLK_;
        unsigned prev = __hip_atomic_fetch_add(cnt, 1u, __ATOMIC_RELAXED, __HIP_MEMORY_SCOPE_AGENT);
        if (prev + 1u < target) {
            while (__hip_atomic_load(cnt, __ATOMIC_RELAXED, __HIP_MEMORY_SCOPE_AGENT) < target)
                __builtin_amdgcn_s_sleep(1);
        }
        asm volatile("" ::: "memory");     // no compiler caching across the barrier
    }
    __syncthreads();
}

__global__ void init_kernel(unsigned* __restrict__ bar) {
    if (threadIdx.x < 8) bar[threadIdx.x] = 0u;
}

__global__ __launch_bounds__(512)
void elastic_kernel(const float* __restrict__ lamb, const float* __restrict__ mu,
                    const float* __restrict__ buoy, const float* __restrict__ amps,
                    const int* __restrict__ src_loc, const int* __restrict__ rec_loc,
                    float* __restrict__ out, float* __restrict__ ws)
{
    const int x = blockIdx.x * 64 + threadIdx.x;   // grid (5,40), block (64,8)
    const int y = blockIdx.y * 8 + threadIdx.y;
    const int c = y * NX_ + x;
    unsigned* bar_cnt = (unsigned*)(ws + BAR_OFF_);
    unsigned  phase = 0;

    // --- PML decay factors, computed in double to match numpy ---
    const double d0 = 3.0 * 1600.0 * log(1000.0) / (2.0 * 20.0 * 4.0);
    double py = 0.0, px = 0.0;
    if (y < 20)             { double t = (20.0 - y) / 20.0;           py = t * t; }
    else if (y >= NY_ - 20) { double t = (y - (NY_ - 1 - 20)) / 20.0; py = t * t; }
    if (x < 20)             { double t = (20.0 - x) / 20.0;           px = t * t; }
    else if (x >= NX_ - 20) { double t = (x - (NX_ - 1 - 20)) / 20.0; px = t * t; }
    const float by = (float)exp(-d0 * py * 4.0e-4);
    const float bx = (float)exp(-d0 * px * 4.0e-4);
    const float bym1 = by - 1.0f, bxm1 = bx - 1.0f;
    const float mk = (y < 2 || y >= NY_ - 2 || x < 2 || x >= NX_ - 2) ? 0.0f : 1.0f;

    const float la  = lamb[c];
    const float muv = mu[c];
    const float bu  = buoy[c];
    const float l2m = la + 2.0f * muv;

    // per-thread source-match bitmask
    unsigned smask = 0;
    for (int s = 0; s < SHOTS_; ++s)
        for (int j = 0; j < NSRC_; ++j) {
            int sy = src_loc[(s * NSRC_ + j) * 2 + 0];
            int sx = src_loc[(s * NSRC_ + j) * 2 + 1];
            if (sy == y && sx == x) smask |= 1u << (s * NSRC_ + j);
        }

    float* pvy[SHOTS_]; float* pvx[SHOTS_]; float* psyy[SHOTS_]; float* psxy[SHOTS_]; float* psxx[SHOTS_];
    #pragma unroll
    for (int s = 0; s < SHOTS_; ++s) {
        pvy[s]  = ws + (0 * SHOTS_ + s) * NP_;
        pvx[s]  = ws + (1 * SHOTS_ + s) * NP_;
        psyy[s] = ws + (2 * SHOTS_ + s) * NP_;
        psxy[s] = ws + (3 * SHOTS_ + s) * NP_;
        psxx[s] = ws + (4 * SHOTS_ + s) * NP_;
    }
    float* rec = ws + REC_OFF_;   // [NT][SHOTS*NREC]

    // wave-field self values + all 8 CPML memory vars live in registers
    float vy[SHOTS_]  = {0, 0}, vx[SHOTS_]  = {0, 0};
    float syy[SHOTS_] = {0, 0}, sxy[SHOTS_] = {0, 0}, sxx[SHOTS_] = {0, 0};
    float msyyy[SHOTS_] = {0, 0}, msxyy[SHOTS_] = {0, 0}, msxyx[SHOTS_] = {0, 0}, msxxx[SHOTS_] = {0, 0};
    float mvyy[SHOTS_]  = {0, 0}, mvyx[SHOTS_]  = {0, 0}, mvxy[SHOTS_]  = {0, 0}, mvxx[SHOTS_]  = {0, 0};

    // zero-init global wave fields (ws is poisoned 0xAA before every launch)
    #pragma unroll
    for (int s = 0; s < SHOTS_; ++s) {
        cst(&pvy[s][c], 0.f); cst(&pvx[s][c], 0.f);
        cst(&psyy[s][c], 0.f); cst(&psxy[s][c], 0.f); cst(&psxx[s][c], 0.f);
    }

    gbar(bar_cnt, ++phase);

    const int  tid      = threadIdx.y * 64 + threadIdx.x;
    const bool recorder = (blockIdx.x == 0 && blockIdx.y == 0);

    for (int t = 0; t < NT_; ++t) {
        // ---------- velocity phase ----------
        #pragma unroll
        for (int s = 0; s < SHOTS_; ++s) {
            const float* S_yy = psyy[s]; const float* S_xy = psxy[s]; const float* S_xx = psxx[s];
            float d, ay, ax;
            // d = D-_y(syy)
            d = (C1_ * (syy[s] - gld(S_yy, y - 1, x)) + C2_ * (gld(S_yy, y + 1, x) - gld(S_yy, y - 2, x))) * IDH_;
            msyyy[s] = by * msyyy[s] + bym1 * d;
            ay = d + msyyy[s];
            // d = D+_x(sxy)
            d = (C1_ * (gld(S_xy, y, x + 1) - sxy[s]) + C2_ * (gld(S_xy, y, x + 2) - gld(S_xy, y, x - 1))) * IDH_;
            msxyx[s] = bx * msxyx[s] + bxm1 * d;
            ay = ay + d + msxyx[s];
            vy[s] = vy[s] + DT_ * bu * ay;
            // d = D-_x(sxx)
            d = (C1_ * (sxx[s] - gld(S_xx, y, x - 1)) + C2_ * (gld(S_xx, y, x + 1) - gld(S_xx, y, x - 2))) * IDH_;
            msxxx[s] = bx * msxxx[s] + bxm1 * d;
            ax = d + msxxx[s];
            // d = D+_y(sxy)
            d = (C1_ * (gld(S_xy, y + 1, x) - sxy[s]) + C2_ * (gld(S_xy, y + 2, x) - gld(S_xy, y - 1, x))) * IDH_;
            msxyy[s] = by * msxyy[s] + bym1 * d;
            ax = ax + d + msxyy[s];
            vx[s] = vx[s] + DT_ * bu * ax;
            // source injection (before mask; sources are interior)
            unsigned m = (smask >> (s * NSRC_)) & 0xFFu;
            if (m) {
                for (int j = 0; j < NSRC_; ++j)
                    if (m & (1u << j)) vy[s] = vy[s] + DT_ * amps[(s * NSRC_ + j) * NT_ + t] * bu;
            }
            vy[s] *= mk; vx[s] *= mk;
            cst(&pvy[s][c], vy[s]); cst(&pvx[s][c], vx[s]);
        }

        gbar(bar_cnt, ++phase);

        // ---------- record receivers (vy is final for this step) ----------
        if (recorder && tid < SHOTS_ * NREC_) {
            int s  = tid / NREC_, r = tid % NREC_;
            int ry = rec_loc[(s * NREC_ + r) * 2 + 0];
            int rx = rec_loc[(s * NREC_ + r) * 2 + 1];
            cst(&rec[t * (SHOTS_ * NREC_) + tid], cld(&pvy[s][ry * NX_ + rx]));
        }

        // ---------- stress phase ----------
        #pragma unroll
        for (int s = 0; s < SHOTS_; ++s) {
            const float* Vy = pvy[s]; const float* Vx = pvx[s];
            float d, e1, e2, g;
            // d = D+_y(vy)
            d = (C1_ * (gld(Vy, y + 1, x) - vy[s]) + C2_ * (gld(Vy, y + 2, x) - gld(Vy, y - 1, x))) * IDH_;
            mvyy[s] = by * mvyy[s] + bym1 * d;
            e1 = d + mvyy[s];
            // d = D-_x(vx)
            d = (C1_ * (vx[s] - gld(Vx, y, x - 1)) + C2_ * (gld(Vx, y, x + 1) - gld(Vx, y, x - 2))) * IDH_;
            mvxx[s] = bx * mvxx[s] + bxm1 * d;
            e2 = d + mvxx[s];
            syy[s] = (syy[s] + DT_ * (l2m * e1 + la * e2)) * mk;
            sxx[s] = (sxx[s] + DT_ * (l2m * e2 + la * e1)) * mk;
            // d = D+_x(vy)
            d = (C1_ * (gld(Vy, y, x + 1) - vy[s]) + C2_ * (gld(Vy, y, x + 2) - gld(Vy, y, x - 1))) * IDH_;
            mvyx[s] = bx * mvyx[s] + bxm1 * d;
            g = d + mvyx[s];
            // d = D-_y(vx)
            d = (C1_ * (vx[s] - gld(Vx, y - 1, x)) + C2_ * (gld(Vx, y + 1, x) - gld(Vx, y - 2, x))) * IDH_;
            mvxy[s] = by * mvxy[s] + bym1 * d;
            g = g + d + mvxy[s];
            sxy[s] = (sxy[s] + DT_ * muv * g) * mk;
            cst(&psyy[s][c], syy[s]); cst(&psxy[s][c], sxy[s]); cst(&psxx[s][c], sxx[s]);
        }

        gbar(bar_cnt, ++phase);
    }

    // ---------- final output: out[s][r][t] = 0.5*(rec[t] + rec[t+1]) ----------
    const int gid = (blockIdx.y * gridDim.x + blockIdx.x) * 512 + tid;
    if (gid < SHOTS_ * NREC_ * (NT_ - 1)) {
        int t  = gid % (NT_ - 1);
        int sr = gid / (NT_ - 1);
        int r  = sr % NREC_;
        int s  = sr / NREC_;
        float a = cld(&rec[t       * (SHOTS_ * NREC_) + s * NREC_ + r]);
        float b = cld(&rec[(t + 1) * (SHOTS_ * NREC_) + s * NREC_ + r]);
        out[gid] = 0.5f * (a + b);
    }
}

extern "C" void kernel_launch(void* const* d_in, const int* in_sizes, int n_in,
                              void* d_out, int out_size, void* d_ws, size_t ws_size,
                              hipStream_t stream)
{
    const float* lamb = (const float*)d_in[0];
    const float* mu   = (const float*)d_in[1];
    const float* buoy = (const float*)d_in[2];
    const float* amps = (const float*)d_in[3];
    const int*   src  = (const int*)d_in[4];
    const int*   recl = (const int*)d_in[5];
    float* out = (float*)d_out;
    float* ws  = (float*)d_ws;

    unsigned* bar = (unsigned*)(ws + BAR_OFF_);
    init_kernel<<<dim3(1), dim3(64), 0, stream>>>(bar);

    dim3 grid(5, 40, 1), block(64, 8, 1);
    elastic_kernel<<<grid, block, 0, stream>>>(lamb, mu, buoy, amps, src, recl, out, ws);
}

// Round 5
// 2167.578 us; speedup vs baseline: 4.2280x; 1.0404x over previous
//
#include <hip/hip_runtime.h>
#include <math.h>

constexpr int NY_ = 320, NX_ = 320, NT_ = 160, SHOTS_ = 2, NSRC_ = 8, NREC_ = 96;
constexpr float DT_  = 4.0e-4f;
constexpr float C1_  = 9.0f / 8.0f;
constexpr float C2_  = -1.0f / 24.0f;
constexpr float IDH_ = 0.25f;           // 1/DH, exact
constexpr int   NP_   = NY_ * NX_;
constexpr unsigned NBLK_ = 200;         // 200 blocks x 512 thr = 102400 = NP_
constexpr int   REC_OFF_ = 10 * NP_;            // floats; rec = NT*SHOTS*NREC = 30720
constexpr int   BAR_OFF_ = 10 * NP_ + 32768;    // floats; 200 arrival flags live here

// ---- coherent (Infinity-Cache-backed) access: relaxed agent-scope atomics
// compile to global_load/store sc0 sc1 -> bypass L1+L2, served by the IF (the
// agent coherence point on multi-XCD gfx950). No cache flushes needed anywhere.
__device__ __forceinline__ float cld(const float* p) {
    return __hip_atomic_load(p, __ATOMIC_RELAXED, __HIP_MEMORY_SCOPE_AGENT);
}
__device__ __forceinline__ void cst(float* p, float v) {
    __hip_atomic_store(p, v, __ATOMIC_RELAXED, __HIP_MEMORY_SCOPE_AGENT);
}
__device__ __forceinline__ unsigned cldu(const unsigned* p) {
    return __hip_atomic_load(p, __ATOMIC_RELAXED, __HIP_MEMORY_SCOPE_AGENT);
}
__device__ __forceinline__ void cstu(unsigned* p, unsigned v) {
    __hip_atomic_store(p, v, __ATOMIC_RELAXED, __HIP_MEMORY_SCOPE_AGENT);
}

// out-of-range taps read 0 — exactly equivalent to jnp.roll wraparound because
// wrapped taps (reach <= 2) always land in the 2-wide edge-masked (zero) border.
__device__ __forceinline__ float gld(const float* __restrict__ p, int y, int x) {
    return ((unsigned)y < (unsigned)NY_ && (unsigned)x < (unsigned)NX_) ? cld(p + y * NX_ + x) : 0.0f;
}

// x-direction tap: neighbor lane's register via shuffle (wave = 64 consecutive
// x at fixed y); global fallback only where lx+dx crosses the wave boundary.
__device__ __forceinline__ float xtap(float self, const float* __restrict__ p,
                                      int y, int x, int dx, int lx) {
    float v = __shfl(self, lx + dx, 64);
    return ((unsigned)(lx + dx) < 64u) ? v : gld(p, y, x + dx);
}

// Grid barrier v3: contention-free arrival flags, hand-rolled poll.
// Each block stores its monotonic phase into flag[bid] (sc1 store, no RMW).
// Wave 0 alone polls all 200 flags (lane i watches i, i+64, i+128, i+192),
// converging via plain 64-lane __all; two ordinary __syncthreads bracket it,
// so every wave executes the identical barrier sequence (no mismatched
// s_barrier pairing — the __syncthreads_count pitfall of the prior attempt).
// Ordering: field stores are sc1 (at IF once vmcnt retires; the entry
// __syncthreads drains vmcnt per wave), flag store issues after an explicit
// vmcnt(0) drain on the storing lane.
__device__ __forceinline__ void gbar(unsigned* flags, int bid, int tid, unsigned phase) {
    __syncthreads();                       // all waves' field stores drained (vmcnt 0)
    if (tid < 64) {
        if (tid == 0) {
            asm volatile("s_waitcnt vmcnt(0)" ::: "memory");
            cstu(&flags[bid], phase);
        }
        for (;;) {
            bool ok = (cldu(&flags[tid])       >= phase)
                   && (cldu(&flags[tid + 64])  >= phase)
                   && (cldu(&flags[tid + 128]) >= phase)
                   && (tid >= 8 || cldu(&flags[tid + 192]) >= phase);
            if (__all(ok)) break;
            __builtin_amdgcn_s_sleep(1);
        }
    }
    __syncthreads();
    asm volatile("" ::: "memory");         // no compiler caching across the barrier
}

__global__ void init_kernel(unsigned* __restrict__ bar) {
    bar[threadIdx.x] = 0u;                 // zero 256 words (flags + padding)
}

__global__ __launch_bounds__(512)
void elastic_kernel(const float* __restrict__ lamb, const float* __restrict__ mu,
                    const float* __restrict__ buoy, const float* __restrict__ amps,
                    const int* __restrict__ src_loc, const int* __restrict__ rec_loc,
                    float* __restrict__ out, float* __restrict__ ws)
{
    const int lx = threadIdx.x;
    const int x = blockIdx.x * 64 + lx;    // grid (5,40), block (64,8)
    const int y = blockIdx.y * 8 + threadIdx.y;
    const int c = y * NX_ + x;
    const int tid = threadIdx.y * 64 + lx;
    const int bid = blockIdx.y * gridDim.x + blockIdx.x;
    unsigned* flags = (unsigned*)(ws + BAR_OFF_);
    unsigned  phase = 0;

    // --- PML decay factors, computed in double to match numpy ---
    const double d0 = 3.0 * 1600.0 * log(1000.0) / (2.0 * 20.0 * 4.0);
    double py = 0.0, px = 0.0;
    if (y < 20)             { double t = (20.0 - y) / 20.0;           py = t * t; }
    else if (y >= NY_ - 20) { double t = (y - (NY_ - 1 - 20)) / 20.0; py = t * t; }
    if (x < 20)             { double t = (20.0 - x) / 20.0;           px = t * t; }
    else if (x >= NX_ - 20) { double t = (x - (NX_ - 1 - 20)) / 20.0; px = t * t; }
    const float by = (float)exp(-d0 * py * 4.0e-4);
    const float bx = (float)exp(-d0 * px * 4.0e-4);
    const float bym1 = by - 1.0f, bxm1 = bx - 1.0f;
    const float mk = (y < 2 || y >= NY_ - 2 || x < 2 || x >= NX_ - 2) ? 0.0f : 1.0f;

    const float la  = lamb[c];
    const float muv = mu[c];
    const float bu  = buoy[c];
    const float l2m = la + 2.0f * muv;

    // per-thread source-match bitmask
    unsigned smask = 0;
    for (int s = 0; s < SHOTS_; ++s)
        for (int j = 0; j < NSRC_; ++j) {
            int sy = src_loc[(s * NSRC_ + j) * 2 + 0];
            int sx = src_loc[(s * NSRC_ + j) * 2 + 1];
            if (sy == y && sx == x) smask |= 1u << (s * NSRC_ + j);
        }

    float* pvy[SHOTS_]; float* pvx[SHOTS_]; float* psyy[SHOTS_]; float* psxy[SHOTS_]; float* psxx[SHOTS_];
    #pragma unroll
    for (int s = 0; s < SHOTS_; ++s) {
        pvy[s]  = ws + (0 * SHOTS_ + s) * NP_;
        pvx[s]  = ws + (1 * SHOTS_ + s) * NP_;
        psyy[s] = ws + (2 * SHOTS_ + s) * NP_;
        psxy[s] = ws + (3 * SHOTS_ + s) * NP_;
        psxx[s] = ws + (4 * SHOTS_ + s) * NP_;
    }
    float* rec = ws + REC_OFF_;   // [NT][SHOTS*NREC]

    // wave-field self values + all 8 CPML memory vars live in registers
    float vy[SHOTS_]  = {0, 0}, vx[SHOTS_]  = {0, 0};
    float syy[SHOTS_] = {0, 0}, sxy[SHOTS_] = {0, 0}, sxx[SHOTS_] = {0, 0};
    float msyyy[SHOTS_] = {0, 0}, msxyy[SHOTS_] = {0, 0}, msxyx[SHOTS_] = {0, 0}, msxxx[SHOTS_] = {0, 0};
    float mvyy[SHOTS_]  = {0, 0}, mvyx[SHOTS_]  = {0, 0}, mvxy[SHOTS_]  = {0, 0}, mvxx[SHOTS_]  = {0, 0};

    // zero-init global wave fields (ws is poisoned 0xAA before every launch)
    #pragma unroll
    for (int s = 0; s < SHOTS_; ++s) {
        cst(&pvy[s][c], 0.f); cst(&pvx[s][c], 0.f);
        cst(&psyy[s][c], 0.f); cst(&psxy[s][c], 0.f); cst(&psxx[s][c], 0.f);
    }

    gbar(flags, bid, tid, ++phase);

    const bool recorder = (bid == 0);

    for (int t = 0; t < NT_; ++t) {
        // ---------- velocity phase ----------
        #pragma unroll
        for (int s = 0; s < SHOTS_; ++s) {
            const float* S_yy = psyy[s]; const float* S_xy = psxy[s]; const float* S_xx = psxx[s];
            float d, ay, ax;
            // d = D-_y(syy)
            d = (C1_ * (syy[s] - gld(S_yy, y - 1, x)) + C2_ * (gld(S_yy, y + 1, x) - gld(S_yy, y - 2, x))) * IDH_;
            msyyy[s] = by * msyyy[s] + bym1 * d;
            ay = d + msyyy[s];
            // d = D+_x(sxy)  (x-taps via wave shuffle)
            d = (C1_ * (xtap(sxy[s], S_xy, y, x, 1, lx) - sxy[s])
               + C2_ * (xtap(sxy[s], S_xy, y, x, 2, lx) - xtap(sxy[s], S_xy, y, x, -1, lx))) * IDH_;
            msxyx[s] = bx * msxyx[s] + bxm1 * d;
            ay = ay + d + msxyx[s];
            vy[s] = vy[s] + DT_ * bu * ay;
            // d = D-_x(sxx)
            d = (C1_ * (sxx[s] - xtap(sxx[s], S_xx, y, x, -1, lx))
               + C2_ * (xtap(sxx[s], S_xx, y, x, 1, lx) - xtap(sxx[s], S_xx, y, x, -2, lx))) * IDH_;
            msxxx[s] = bx * msxxx[s] + bxm1 * d;
            ax = d + msxxx[s];
            // d = D+_y(sxy)
            d = (C1_ * (gld(S_xy, y + 1, x) - sxy[s]) + C2_ * (gld(S_xy, y + 2, x) - gld(S_xy, y - 1, x))) * IDH_;
            msxyy[s] = by * msxyy[s] + bym1 * d;
            ax = ax + d + msxyy[s];
            vx[s] = vx[s] + DT_ * bu * ax;
            // source injection (before mask; sources are interior)
            unsigned m = (smask >> (s * NSRC_)) & 0xFFu;
            if (m) {
                for (int j = 0; j < NSRC_; ++j)
                    if (m & (1u << j)) vy[s] = vy[s] + DT_ * amps[(s * NSRC_ + j) * NT_ + t] * bu;
            }
            vy[s] *= mk; vx[s] *= mk;
            cst(&pvy[s][c], vy[s]); cst(&pvx[s][c], vx[s]);
        }

        gbar(flags, bid, tid, ++phase);

        // ---------- record receivers (vy is final for this step) ----------
        if (recorder && tid < SHOTS_ * NREC_) {
            int s  = tid / NREC_, r = tid % NREC_;
            int ry = rec_loc[(s * NREC_ + r) * 2 + 0];
            int rx = rec_loc[(s * NREC_ + r) * 2 + 1];
            cst(&rec[t * (SHOTS_ * NREC_) + tid], cld(&pvy[s][ry * NX_ + rx]));
        }

        // ---------- stress phase ----------
        #pragma unroll
        for (int s = 0; s < SHOTS_; ++s) {
            const float* Vy = pvy[s]; const float* Vx = pvx[s];
            float d, e1, e2, g;
            // d = D+_y(vy)
            d = (C1_ * (gld(Vy, y + 1, x) - vy[s]) + C2_ * (gld(Vy, y + 2, x) - gld(Vy, y - 1, x))) * IDH_;
            mvyy[s] = by * mvyy[s] + bym1 * d;
            e1 = d + mvyy[s];
            // d = D-_x(vx)
            d = (C1_ * (vx[s] - xtap(vx[s], Vx, y, x, -1, lx))
               + C2_ * (xtap(vx[s], Vx, y, x, 1, lx) - xtap(vx[s], Vx, y, x, -2, lx))) * IDH_;
            mvxx[s] = bx * mvxx[s] + bxm1 * d;
            e2 = d + mvxx[s];
            syy[s] = (syy[s] + DT_ * (l2m * e1 + la * e2)) * mk;
            sxx[s] = (sxx[s] + DT_ * (l2m * e2 + la * e1)) * mk;
            // d = D+_x(vy)
            d = (C1_ * (xtap(vy[s], Vy, y, x, 1, lx) - vy[s])
               + C2_ * (xtap(vy[s], Vy, y, x, 2, lx) - xtap(vy[s], Vy, y, x, -1, lx))) * IDH_;
            mvyx[s] = bx * mvyx[s] + bxm1 * d;
            g = d + mvyx[s];
            // d = D-_y(vx)
            d = (C1_ * (vx[s] - gld(Vx, y - 1, x)) + C2_ * (gld(Vx, y + 1, x) - gld(Vx, y - 2, x))) * IDH_;
            mvxy[s] = by * mvxy[s] + bym1 * d;
            g = g + d + mvxy[s];
            sxy[s] = (sxy[s] + DT_ * muv * g) * mk;
            cst(&psyy[s][c], syy[s]); cst(&psxy[s][c], sxy[s]); cst(&psxx[s][c], sxx[s]);
        }

        gbar(flags, bid, tid, ++phase);
    }

    // ---------- final output: out[s][r][t] = 0.5*(rec[t] + rec[t+1]) ----------
    const int gid = bid * 512 + tid;
    if (gid < SHOTS_ * NREC_ * (NT_ - 1)) {
        int t  = gid % (NT_ - 1);
        int sr = gid / (NT_ - 1);
        int r  = sr % NREC_;
        int s  = sr / NREC_;
        float a = cld(&rec[t       * (SHOTS_ * NREC_) + s * NREC_ + r]);
        float b = cld(&rec[(t + 1) * (SHOTS_ * NREC_) + s * NREC_ + r]);
        out[gid] = 0.5f * (a + b);
    }
}

extern "C" void kernel_launch(void* const* d_in, const int* in_sizes, int n_in,
                              void* d_out, int out_size, void* d_ws, size_t ws_size,
                              hipStream_t stream)
{
    const float* lamb = (const float*)d_in[0];
    const float* mu   = (const float*)d_in[1];
    const float* buoy = (const float*)d_in[2];
    const float* amps = (const float*)d_in[3];
    const int*   src  = (const int*)d_in[4];
    const int*   recl = (const int*)d_in[5];
    float* out = (float*)d_out;
    float* ws  = (float*)d_ws;

    unsigned* bar = (unsigned*)(ws + BAR_OFF_);
    init_kernel<<<dim3(1), dim3(256), 0, stream>>>(bar);

    dim3 grid(5, 40, 1), block(64, 8, 1);
    elastic_kernel<<<grid, block, 0, stream>>>(lamb, mu, buoy, amps, src, recl, out, ws);
}

// Round 6
// 1320.501 us; speedup vs baseline: 6.9403x; 1.6415x over previous
//
#include <hip/hip_runtime.h>
#include <math.h>

constexpr int NY_ = 320, NX_ = 320, NT_ = 160, SHOTS_ = 2, NSRC_ = 8, NREC_ = 96;
constexpr float DT_  = 4.0e-4f;
constexpr float C1_  = 9.0f / 8.0f;
constexpr float C2_  = -1.0f / 24.0f;
constexpr float IDH_ = 0.25f;           // 1/DH, exact
constexpr int NP_     = NY_ * NX_;
constexpr int NSTRIP_ = 40;             // 8-row strips per shot
constexpr int NBLK_   = SHOTS_ * NSTRIP_;
// ws layout (float words): 4 global halo-mirror fields x 2 shots, rec, flags
constexpr int REC_OFF_ = 8 * NP_;                          // [s][r][t] float
constexpr int FLG_OFF_ = 8 * NP_ + SHOTS_ * NREC_ * NT_;   // V[80] then S[80] (unsigned)
constexpr int WS_WORDS_ = FLG_OFF_ + 256;

// ---- coherent (IF-backed) access: relaxed agent-scope atomics -> sc0 sc1,
// bypass L1/L2, served at the agent coherence point. No cache flushes needed.
__device__ __forceinline__ float cld(const float* p) {
    return __hip_atomic_load(p, __ATOMIC_RELAXED, __HIP_MEMORY_SCOPE_AGENT);
}
__device__ __forceinline__ void cst(float* p, float v) {
    __hip_atomic_store(p, v, __ATOMIC_RELAXED, __HIP_MEMORY_SCOPE_AGENT);
}
__device__ __forceinline__ unsigned cldu(const unsigned* p) {
    return __hip_atomic_load(p, __ATOMIC_RELAXED, __HIP_MEMORY_SCOPE_AGENT);
}
__device__ __forceinline__ void cstu(unsigned* p, unsigned v) {
    __hip_atomic_store(p, v, __ATOMIC_RELAXED, __HIP_MEMORY_SCOPE_AGENT);
}

// guarded halo import load: out-of-grid rows read 0 (== masked border / roll equivalence)
__device__ __forceinline__ float gldf(const float* p, int y, int c) {
    return ((unsigned)y < (unsigned)NY_) ? cld(p + y * NX_ + c) : 0.0f;
}
// guarded LDS x-tap: out-of-grid cols read 0
__device__ __forceinline__ float ltap(const float (*A)[NX_], int ly, int c) {
    return ((unsigned)c < (unsigned)NX_) ? A[ly][c] : 0.0f;
}
// register x-tap via wave shuffle: cur = this cell's column group, adj = the
// adjacent group's value in the SAME thread (cells are 64-col interleaved)
__device__ __forceinline__ float shtap(float cur, float adj, int lane, int dx) {
    int idx = (lane + dx) & 63;
    float a = __shfl(cur, idx, 64);
    float b = __shfl(adj, idx, 64);
    return ((unsigned)(lane + dx) < 64u) ? a : b;
}

// P2P neighbor sync: wave 0 polls left/right strip flags; bracketed by
// __syncthreads (the round-5-verified pattern; no __syncthreads_count).
__device__ __forceinline__ void pollNbr(const unsigned* f, int sbase, int j,
                                        unsigned tgt, int tid) {
    __syncthreads();
    if (tid < 64) {
        for (;;) {
            bool ok = true;
            if (tid == 0 && j > 0)           ok = cldu(&f[sbase + j - 1]) >= tgt;
            else if (tid == 1 && j < NSTRIP_ - 1) ok = cldu(&f[sbase + j + 1]) >= tgt;
            if (__all(ok)) break;
            __builtin_amdgcn_s_sleep(1);
        }
    }
    __syncthreads();
    asm volatile("" ::: "memory");
}

__global__ void init_kernel(float* __restrict__ ws) {
    for (int i = blockIdx.x * 256 + threadIdx.x; i < WS_WORDS_; i += gridDim.x * 256)
        ws[i] = 0.0f;
}

__global__ __launch_bounds__(512)
void elastic_kernel(const float* __restrict__ lamb, const float* __restrict__ mu,
                    const float* __restrict__ buoy, const float* __restrict__ amps,
                    const int* __restrict__ src_loc, const int* __restrict__ rec_loc,
                    float* __restrict__ out, float* __restrict__ ws)
{
    __shared__ float Lvy[12][NX_], Lvx[12][NX_], Lsyy[12][NX_], Lsxy[12][NX_];

    const int tid  = threadIdx.x;
    const int lane = tid & 63;
    const int w    = tid >> 6;          // local row 0..7 (one wave per row)
    const int bid  = blockIdx.x;
    const int s    = bid / NSTRIP_;
    const int j    = bid % NSTRIP_;
    const int r0   = j * 8;
    const int gy   = r0 + w;            // this thread's global row
    const int ly   = w + 2;             // LDS row (halo rows 0,1,10,11)

    float* gVy  = ws + (0 * SHOTS_ + s) * NP_;
    float* gVx  = ws + (1 * SHOTS_ + s) * NP_;
    float* gSyy = ws + (2 * SHOTS_ + s) * NP_;
    float* gSxy = ws + (3 * SHOTS_ + s) * NP_;
    float* recp = ws + REC_OFF_ + (s * NREC_ + tid) * NT_;   // valid only if tid<96
    unsigned* flgV = (unsigned*)(ws + FLG_OFF_);
    unsigned* flgS = flgV + NBLK_;
    const int sbase = s * NSTRIP_;

    // --- per-cell loop invariants (k = column group, col = 64k+lane) ---
    const double d0 = 3.0 * 1600.0 * log(1000.0) / (2.0 * 20.0 * 4.0);
    double py = 0.0;
    if (gy < 20)             { double u = (20.0 - gy) / 20.0;           py = u * u; }
    else if (gy >= NY_ - 20) { double u = (gy - (NY_ - 1 - 20)) / 20.0; py = u * u; }
    const float by = (float)exp(-d0 * py * 4.0e-4);
    const float bym1 = by - 1.0f;

    float bx[5], bxm1[5], mk[5], la[5], muv[5], bu[5], l2m[5];
    #pragma unroll
    for (int k = 0; k < 5; ++k) {
        int c = 64 * k + lane;
        double px = 0.0;
        if (c < 20)             { double u = (20.0 - c) / 20.0;           px = u * u; }
        else if (c >= NX_ - 20) { double u = (c - (NX_ - 1 - 20)) / 20.0; px = u * u; }
        bx[k] = (float)exp(-d0 * px * 4.0e-4);
        bxm1[k] = bx[k] - 1.0f;
        mk[k] = (gy < 2 || gy >= NY_ - 2 || c < 2 || c >= NX_ - 2) ? 0.0f : 1.0f;
        la[k]  = lamb[gy * NX_ + c];
        muv[k] = mu[gy * NX_ + c];
        bu[k]  = buoy[gy * NX_ + c];
        l2m[k] = la[k] + 2.0f * muv[k];
    }

    // per-thread source mask: bit (8*k + js) set if cell k owns source js of shot s
    unsigned long long sm = 0ull;
    for (int js = 0; js < NSRC_; ++js) {
        int sy = src_loc[(s * NSRC_ + js) * 2 + 0];
        int sx = src_loc[(s * NSRC_ + js) * 2 + 1];
        if (sy == gy && (sx & 63) == lane) sm |= 1ull << (8 * (sx >> 6) + js);
    }
    // per-thread receiver (tid<96 handles receiver tid of this shot)
    bool myrec = false; int rl = 0;
    if (tid < NREC_) {
        int ry = rec_loc[(s * NREC_ + tid) * 2 + 0];
        int rx = rec_loc[(s * NREC_ + tid) * 2 + 1];
        if ((ry >> 3) == j) { myrec = true; rl = ((ry & 7) + 2) * NX_ + rx; }
    }

    // zero LDS fields (fields start at 0)
    for (int i = tid; i < 12 * NX_; i += 512) {
        ((float*)Lvy)[i] = 0.f; ((float*)Lvx)[i] = 0.f;
        ((float*)Lsyy)[i] = 0.f; ((float*)Lsxy)[i] = 0.f;
    }

    // register state: 5 wave-field self values + sxx + 8 CPML vars per cell
    float vy[5] = {}, vx[5] = {}, syy[5] = {}, sxy[5] = {}, sxx[5] = {};
    float msyyy[5] = {}, msxyy[5] = {}, msxyx[5] = {}, msxxx[5] = {};
    float mvyy[5] = {}, mvyx[5] = {}, mvxy[5] = {}, mvxx[5] = {};

    for (int t = 0; t < NT_; ++t) {
        // ================= velocity phase =================
        pollNbr(flgS, sbase, j, (unsigned)t, tid);   // neighbor stress(t-1) published

        if (tid < NX_) {  // import stress halo rows into LDS (batched loads, then writes)
            int c = tid;
            float a0 = gldf(gSyy, r0 - 2, c), a1 = gldf(gSyy, r0 - 1, c), a2 = gldf(gSyy, r0 + 8, c);
            float b0 = gldf(gSxy, r0 - 1, c), b1 = gldf(gSxy, r0 + 8, c), b2 = gldf(gSxy, r0 + 9, c);
            Lsyy[0][c] = a0; Lsyy[1][c] = a1; Lsyy[10][c] = a2;
            Lsxy[1][c] = b0; Lsxy[10][c] = b1; Lsxy[11][c] = b2;
        }
        __syncthreads();

        #pragma unroll
        for (int k = 0; k < 5; ++k) {
            const int c = 64 * k + lane;
            const float sxxp = (k < 4) ? sxx[k + 1] : 0.0f;
            const float sxxm = (k > 0) ? sxx[k - 1] : 0.0f;
            float d, ay, ax;
            // D-_y(syy)
            d = (C1_ * (syy[k] - Lsyy[ly - 1][c]) + C2_ * (Lsyy[ly + 1][c] - Lsyy[ly - 2][c])) * IDH_;
            msyyy[k] = by * msyyy[k] + bym1 * d;
            ay = d + msyyy[k];
            // D+_x(sxy)
            d = (C1_ * (ltap(Lsxy, ly, c + 1) - sxy[k])
               + C2_ * (ltap(Lsxy, ly, c + 2) - ltap(Lsxy, ly, c - 1))) * IDH_;
            msxyx[k] = bx[k] * msxyx[k] + bxm1[k] * d;
            ay = ay + d + msxyx[k];
            vy[k] = vy[k] + DT_ * bu[k] * ay;
            // D-_x(sxx)  (register shuffles — sxx never leaves registers)
            d = (C1_ * (sxx[k] - shtap(sxx[k], sxxm, lane, -1))
               + C2_ * (shtap(sxx[k], sxxp, lane, 1) - shtap(sxx[k], sxxm, lane, -2))) * IDH_;
            msxxx[k] = bx[k] * msxxx[k] + bxm1[k] * d;
            ax = d + msxxx[k];
            // D+_y(sxy)
            d = (C1_ * (Lsxy[ly + 1][c] - sxy[k]) + C2_ * (Lsxy[ly + 2][c] - Lsxy[ly - 1][c])) * IDH_;
            msxyy[k] = by * msxyy[k] + bym1 * d;
            ax = ax + d + msxyy[k];
            vx[k] = vx[k] + DT_ * bu[k] * ax;
            // source injection (interior; commutes with mask)
            unsigned m = (unsigned)(sm >> (8 * k)) & 0xFFu;
            if (m) {
                for (int js = 0; js < NSRC_; ++js)
                    if (m & (1u << js)) vy[k] += DT_ * amps[(s * NSRC_ + js) * NT_ + t] * bu[k];
            }
            vy[k] *= mk[k]; vx[k] *= mk[k];
            Lvy[ly][c] = vy[k]; Lvx[ly][c] = vx[k];
        }
        __syncthreads();

        // record receivers (strip-local, same thread writes & later reads)
        if (myrec) recp[t] = ((const float*)Lvy)[rl];

        // publish velocity halo rows (rows read by neighbors' y-taps)
        if (tid < NX_) {
            int c = tid;
            float v0 = Lvy[2][c], v1 = Lvy[3][c], v2 = Lvy[9][c];
            float u0 = Lvx[2][c], u1 = Lvx[8][c], u2 = Lvx[9][c];
            cst(&gVy[(r0 + 0) * NX_ + c], v0);
            cst(&gVy[(r0 + 1) * NX_ + c], v1);
            cst(&gVy[(r0 + 7) * NX_ + c], v2);
            cst(&gVx[(r0 + 0) * NX_ + c], u0);
            cst(&gVx[(r0 + 6) * NX_ + c], u1);
            cst(&gVx[(r0 + 7) * NX_ + c], u2);
        }
        __syncthreads();
        if (tid == 0) {
            asm volatile("s_waitcnt vmcnt(0)" ::: "memory");
            cstu(&flgV[sbase + j], (unsigned)(t + 1));
        }

        // ================= stress phase =================
        pollNbr(flgV, sbase, j, (unsigned)(t + 1), tid);   // neighbor velocity(t) published

        if (tid < NX_) {  // import velocity halo rows
            int c = tid;
            float a0 = gldf(gVy, r0 - 1, c), a1 = gldf(gVy, r0 + 8, c), a2 = gldf(gVy, r0 + 9, c);
            float b0 = gldf(gVx, r0 - 2, c), b1 = gldf(gVx, r0 - 1, c), b2 = gldf(gVx, r0 + 8, c);
            Lvy[1][c] = a0; Lvy[10][c] = a1; Lvy[11][c] = a2;
            Lvx[0][c] = b0; Lvx[1][c] = b1; Lvx[10][c] = b2;
        }
        __syncthreads();

        #pragma unroll
        for (int k = 0; k < 5; ++k) {
            const int c = 64 * k + lane;
            float d, e1, e2, g;
            // D+_y(vy)
            d = (C1_ * (Lvy[ly + 1][c] - vy[k]) + C2_ * (Lvy[ly + 2][c] - Lvy[ly - 1][c])) * IDH_;
            mvyy[k] = by * mvyy[k] + bym1 * d;
            e1 = d + mvyy[k];
            // D-_x(vx)
            d = (C1_ * (vx[k] - ltap(Lvx, ly, c - 1))
               + C2_ * (ltap(Lvx, ly, c + 1) - ltap(Lvx, ly, c - 2))) * IDH_;
            mvxx[k] = bx[k] * mvxx[k] + bxm1[k] * d;
            e2 = d + mvxx[k];
            syy[k] = (syy[k] + DT_ * (l2m[k] * e1 + la[k] * e2)) * mk[k];
            sxx[k] = (sxx[k] + DT_ * (l2m[k] * e2 + la[k] * e1)) * mk[k];
            // D+_x(vy)
            d = (C1_ * (ltap(Lvy, ly, c + 1) - vy[k])
               + C2_ * (ltap(Lvy, ly, c + 2) - ltap(Lvy, ly, c - 1))) * IDH_;
            mvyx[k] = bx[k] * mvyx[k] + bxm1[k] * d;
            g = d + mvyx[k];
            // D-_y(vx)
            d = (C1_ * (vx[k] - Lvx[ly - 1][c]) + C2_ * (Lvx[ly + 1][c] - Lvx[ly - 2][c])) * IDH_;
            mvxy[k] = by * mvxy[k] + bym1 * d;
            g = g + d + mvxy[k];
            sxy[k] = (sxy[k] + DT_ * muv[k] * g) * mk[k];
            Lsyy[ly][c] = syy[k]; Lsxy[ly][c] = sxy[k];
        }
        __syncthreads();

        // publish stress halo rows
        if (tid < NX_) {
            int c = tid;
            float a0 = Lsyy[2][c], a1 = Lsyy[8][c], a2 = Lsyy[9][c];
            float b0 = Lsxy[2][c], b1 = Lsxy[3][c], b2 = Lsxy[9][c];
            cst(&gSyy[(r0 + 0) * NX_ + c], a0);
            cst(&gSyy[(r0 + 6) * NX_ + c], a1);
            cst(&gSyy[(r0 + 7) * NX_ + c], a2);
            cst(&gSxy[(r0 + 0) * NX_ + c], b0);
            cst(&gSxy[(r0 + 1) * NX_ + c], b1);
            cst(&gSxy[(r0 + 7) * NX_ + c], b2);
        }
        __syncthreads();
        if (tid == 0) {
            asm volatile("s_waitcnt vmcnt(0)" ::: "memory");
            cstu(&flgS[sbase + j], (unsigned)(t + 1));
        }
    }

    // ---------- final output: out[s][r][t] = 0.5*(rec[t] + rec[t+1]) ----------
    if (myrec) {
        float* op = out + (s * NREC_ + tid) * (NT_ - 1);
        for (int t = 0; t < NT_ - 1; ++t) op[t] = 0.5f * (recp[t] + recp[t + 1]);
    }
}

extern "C" void kernel_launch(void* const* d_in, const int* in_sizes, int n_in,
                              void* d_out, int out_size, void* d_ws, size_t ws_size,
                              hipStream_t stream)
{
    const float* lamb = (const float*)d_in[0];
    const float* mu   = (const float*)d_in[1];
    const float* buoy = (const float*)d_in[2];
    const float* amps = (const float*)d_in[3];
    const int*   src  = (const int*)d_in[4];
    const int*   recl = (const int*)d_in[5];
    float* out = (float*)d_out;
    float* ws  = (float*)d_ws;

    init_kernel<<<dim3(512), dim3(256), 0, stream>>>(ws);
    elastic_kernel<<<dim3(NBLK_), dim3(512), 0, stream>>>(lamb, mu, buoy, amps, src, recl, out, ws);
}